// Round 10
// baseline (510.025 us; speedup 1.0000x reference)
//
#include <hip/hip_runtime.h>
#include <hip/hip_bf16.h>
#include <hip/hip_cooperative_groups.h>

#define EDGES  500000
#define NNODES 100000
#define QN     256
#define RN     401
#define DD     64
#define AA     64
#define OO     64
#define XSB    1563      // ceil(NNODES/64) virtual blocks for xs/out phases
#define PB     1604      // (QN*RN)/64 virtual blocks for p-phase (exact)
#define EVB    62500     // EDGES/8 virtual blocks for edge-phase (exact)

typedef __attribute__((ext_vector_type(8))) short short8;
typedef __attribute__((ext_vector_type(2))) short short2v;
typedef __attribute__((ext_vector_type(4))) float f32x4;
typedef __attribute__((ext_vector_type(2))) float f32x2;

__device__ inline unsigned short f2bf(float f) {
    union { float f; unsigned int u; } v; v.f = f;
    unsigned int u = v.u;
    u += 0x7FFFu + ((u >> 16) & 1u);   // round-to-nearest-even
    return (unsigned short)(u >> 16);
}

__device__ inline f32x2 bfpair2f(unsigned int u) {
    union { unsigned int i; float f; } lo, hi;
    lo.i = u << 16;
    hi.i = u & 0xFFFF0000u;
    f32x2 r; r[0] = lo.f; r[1] = hi.f; return r;
}

__device__ inline short8 load8_cvt(const float* __restrict__ p) {
    f32x4 x0 = ((const f32x4*)p)[0];
    f32x4 x1 = ((const f32x4*)p)[1];
    short8 r;
    r[0] = (short)f2bf(x0[0]); r[1] = (short)f2bf(x0[1]);
    r[2] = (short)f2bf(x0[2]); r[3] = (short)f2bf(x0[3]);
    r[4] = (short)f2bf(x1[0]); r[5] = (short)f2bf(x1[1]);
    r[6] = (short)f2bf(x1[2]); r[7] = (short)f2bf(x1[3]);
    return r;
}

__device__ inline short8 load8_cvt_prod(const float* __restrict__ pa,
                                        const float* __restrict__ pb) {
    f32x4 a0 = ((const f32x4*)pa)[0];
    f32x4 a1 = ((const f32x4*)pa)[1];
    f32x4 b0 = ((const f32x4*)pb)[0];
    f32x4 b1 = ((const f32x4*)pb)[1];
    short8 r;
    r[0] = (short)f2bf(a0[0]*b0[0]); r[1] = (short)f2bf(a0[1]*b0[1]);
    r[2] = (short)f2bf(a0[2]*b0[2]); r[3] = (short)f2bf(a0[3]*b0[3]);
    r[4] = (short)f2bf(a1[0]*b1[0]); r[5] = (short)f2bf(a1[1]*b1[1]);
    r[6] = (short)f2bf(a1[2]*b1[2]); r[7] = (short)f2bf(a1[3]*b1[3]);
    return r;
}

// packed bf16x2 atomic add (global_atomic_pk_add_bf16, gfx90a+/CDNA4)
__device__ inline void atomic_pk_add_bf16(short* addr, short2v v) {
#if __has_builtin(__builtin_amdgcn_global_atomic_fadd_v2bf16)
    __builtin_amdgcn_global_atomic_fadd_v2bf16(
        (__attribute__((address_space(1))) short2v*)addr, v);
#else
    asm volatile("global_atomic_pk_add_bf16 %0, %1, off"
                 :: "v"(addr), "v"(v) : "memory");
#endif
}

struct Params {
    const float* hidden; const float* Ws_W; const float* q_emb; const float* rela;
    const float* Wq_W;   const float* Wr_W; const float* Wqr_W; const float* Ws_b;
    const int*   edges;  const float* wa_W; const float* wa_b;  const float* Wh_W;
    short* Xs; short* hidden_bf; short* P; short* agg;
    float* out; float* alpha_out;
};

// ---------------------------------------------------------------------------
// MEGA (cooperative): A1 (Xs + hidden_bf + zero agg) -> A2 (P) -> grid.sync ->
//       B (edge alpha + pk-atomic scatter) -> grid.sync -> C (out = agg@Wh^T)
// Grid-stride on gridDim.x — correct for any co-resident grid size.
// ---------------------------------------------------------------------------
__global__ void __launch_bounds__(256, 4) mega(Params pr) {
    __shared__ short smem[AA * 200];
    const int tid  = threadIdx.x;
    const int wave = tid >> 6, lane = tid & 63;
    const int quad = lane >> 4, l15 = lane & 15;
    const int G = gridDim.x;

    // ================= Phase A1: Xs = hidden @ Ws^T, emit hidden_bf, zero agg
    for (int idx = tid; idx < AA * DD; idx += 256) {
        int a = idx >> 6, d = idx & 63;
        smem[a * 72 + d] = (short)f2bf(pr.Ws_W[idx]);
    }
    __syncthreads();
    for (int vb = blockIdx.x; vb < XSB; vb += G) {
        int rowbase_blk = vb * 64;
        {   // zero agg rows owned by this vb
            const short8 z = short8{0,0,0,0,0,0,0,0};
            int base = rowbase_blk * DD + tid * 16;
            int row0 = rowbase_blk + (tid >> 2);
            if (row0 < NNODES) {
                *(short8*)(pr.agg + base) = z;
                *(short8*)(pr.agg + base + 8) = z;
            }
        }
        int rowbase = rowbase_blk + wave * 16;
        int row_a = rowbase + l15;
        f32x4 acc[4];
        for (int t = 0; t < 4; ++t) { acc[t][0]=acc[t][1]=acc[t][2]=acc[t][3]=0.f; }
#pragma unroll
        for (int ks = 0; ks < 2; ++ks) {
            int ka = ks * 32 + quad * 8;
            short8 afrag;
            if (row_a < NNODES) {
                afrag = load8_cvt(pr.hidden + (size_t)row_a * DD + ka);
                *(short8*)(pr.hidden_bf + (size_t)row_a * DD + ka) = afrag;
            } else {
                afrag = short8{0,0,0,0,0,0,0,0};
            }
#pragma unroll
            for (int t = 0; t < 4; ++t) {
                short8 bfrag = *(const short8*)&smem[(t * 16 + l15) * 72 + ka];
                acc[t] = __builtin_amdgcn_mfma_f32_16x16x32_bf16(afrag, bfrag, acc[t], 0, 0, 0);
            }
        }
#pragma unroll
        for (int t = 0; t < 4; ++t)
#pragma unroll
            for (int r = 0; r < 4; ++r) {
                int row = rowbase + quad * 4 + r;
                if (row < NNODES)
                    pr.Xs[(size_t)row * AA + t * 16 + l15] = (short)f2bf(acc[t][r]);
            }
    }
    __syncthreads();

    // ================= Phase A2: P = Ws_b + concat(hq,hr,hq*hr) @ W3^T (K=192)
    for (int idx = tid; idx < AA * 192; idx += 256) {
        int a = idx / 192, k = idx - a * 192;
        float v = (k < 64) ? pr.Wq_W[a * 64 + k]
                : (k < 128) ? pr.Wr_W[a * 64 + (k - 64)]
                            : pr.Wqr_W[a * 64 + (k - 128)];
        smem[a * 200 + k] = (short)f2bf(v);
    }
    __syncthreads();
    for (int vb = blockIdx.x; vb < PB; vb += G) {
        int pairbase = vb * 64 + wave * 16;
        int mypair = pairbase + l15;
        int q = mypair / RN;
        int r = mypair - q * RN;
        const float* hq = pr.q_emb + (size_t)q * DD;
        const float* hr = pr.rela  + (size_t)r * DD;
        f32x4 acc[4];
#pragma unroll
        for (int t = 0; t < 4; ++t) {
            float b = pr.Ws_b[t * 16 + l15];
            acc[t][0] = acc[t][1] = acc[t][2] = acc[t][3] = b;
        }
#pragma unroll
        for (int ks = 0; ks < 6; ++ks) {
            int ka = ks * 32 + quad * 8;
            short8 afrag;
            if (ka < 64)       afrag = load8_cvt(hq + ka);
            else if (ka < 128) afrag = load8_cvt(hr + (ka - 64));
            else               afrag = load8_cvt_prod(hq + (ka - 128), hr + (ka - 128));
#pragma unroll
            for (int t = 0; t < 4; ++t) {
                short8 bfrag = *(const short8*)&smem[(t * 16 + l15) * 200 + ka];
                acc[t] = __builtin_amdgcn_mfma_f32_16x16x32_bf16(afrag, bfrag, acc[t], 0, 0, 0);
            }
        }
#pragma unroll
        for (int t = 0; t < 4; ++t)
#pragma unroll
            for (int rg = 0; rg < 4; ++rg) {
                int row = pairbase + quad * 4 + rg;
                pr.P[(size_t)row * AA + t * 16 + l15] = (short)f2bf(acc[t][rg]);
            }
    }

    __threadfence();                       // agent-scope release (L2 writeback)
    cooperative_groups::this_grid().sync();

    // ================= Phase B: per-edge alpha + pk-atomic scatter
    {
        const int l32 = lane & 31;
        const int half = lane >> 5;
        const int c2 = 2 * l32;
        const f32x2 wa = *(const f32x2*)&pr.wa_W[c2];
        const float wab = pr.wa_b[0];
        for (int vb = blockIdx.x; vb < EVB; vb += 2 * G) {
            int vbB = vb + G;
            bool hasB = vbB < EVB;
            size_t eA = (size_t)vb * 8 + wave * 2 + half;
            size_t eB = (size_t)(hasB ? vbB : vb) * 8 + wave * 2 + half;
            const int* epA = pr.edges + eA * 6;
            const int* epB = pr.edges + eB * 6;
            int qA = epA[0], rA = epA[2];
            int2 soA = *(const int2*)&epA[4];
            int qB = epB[0], rB = epB[2];
            int2 soB = *(const int2*)&epB[4];
            unsigned xsA = *(const unsigned*)&pr.Xs[(size_t)soA.x * AA + c2];
            unsigned ppA = *(const unsigned*)&pr.P[((size_t)qA * RN + rA) * AA + c2];
            unsigned hsA = *(const unsigned*)&pr.hidden_bf[(size_t)soA.x * DD + c2];
            f32x2 hrA = *(const f32x2*)&pr.rela[(size_t)rA * DD + c2];
            unsigned xsB = *(const unsigned*)&pr.Xs[(size_t)soB.x * AA + c2];
            unsigned ppB = *(const unsigned*)&pr.P[((size_t)qB * RN + rB) * AA + c2];
            unsigned hsB = *(const unsigned*)&pr.hidden_bf[(size_t)soB.x * DD + c2];
            f32x2 hrB = *(const f32x2*)&pr.rela[(size_t)rB * DD + c2];
            {
                f32x2 xs = bfpair2f(xsA), pp = bfpair2f(ppA);
                float v = fmaxf(xs[0] + pp[0], 0.f) * wa[0]
                        + fmaxf(xs[1] + pp[1], 0.f) * wa[1];
#pragma unroll
                for (int off = 16; off > 0; off >>= 1) v += __shfl_xor(v, off, 64);
                float alpha = 1.f / (1.f + __expf(-(v + wab)));
                if (l32 == 0) pr.alpha_out[eA] = alpha;
                f32x2 hs = bfpair2f(hsA);
                short2v m;
                m[0] = (short)f2bf(alpha * hs[0] * hrA[0]);
                m[1] = (short)f2bf(alpha * hs[1] * hrA[1]);
                atomic_pk_add_bf16(pr.agg + (size_t)soA.y * DD + c2, m);
            }
            if (hasB) {
                f32x2 xs = bfpair2f(xsB), pp = bfpair2f(ppB);
                float v = fmaxf(xs[0] + pp[0], 0.f) * wa[0]
                        + fmaxf(xs[1] + pp[1], 0.f) * wa[1];
#pragma unroll
                for (int off = 16; off > 0; off >>= 1) v += __shfl_xor(v, off, 64);
                float alpha = 1.f / (1.f + __expf(-(v + wab)));
                if (l32 == 0) pr.alpha_out[eB] = alpha;
                f32x2 hs = bfpair2f(hsB);
                short2v m;
                m[0] = (short)f2bf(alpha * hs[0] * hrB[0]);
                m[1] = (short)f2bf(alpha * hs[1] * hrB[1]);
                atomic_pk_add_bf16(pr.agg + (size_t)soB.y * DD + c2, m);
            }
        }
    }

    __threadfence();                       // publish atomic results
    cooperative_groups::this_grid().sync();

    // ================= Phase C: out = agg @ Wh^T
    __syncthreads();
    for (int idx = tid; idx < OO * DD; idx += 256) {
        int o = idx >> 6, d = idx & 63;
        smem[o * 72 + d] = (short)f2bf(pr.Wh_W[idx]);
    }
    __syncthreads();
    for (int vb = blockIdx.x; vb < XSB; vb += G) {
        int rowbase = vb * 64 + wave * 16;
        int row_a = rowbase + l15;
        f32x4 acc[4];
        for (int t = 0; t < 4; ++t) { acc[t][0]=acc[t][1]=acc[t][2]=acc[t][3]=0.f; }
#pragma unroll
        for (int ks = 0; ks < 2; ++ks) {
            int ka = ks * 32 + quad * 8;
            short8 afrag;
            if (row_a < NNODES) afrag = *(const short8*)(pr.agg + (size_t)row_a * DD + ka);
            else                afrag = short8{0,0,0,0,0,0,0,0};
#pragma unroll
            for (int t = 0; t < 4; ++t) {
                short8 bfrag = *(const short8*)&smem[(t * 16 + l15) * 72 + ka];
                acc[t] = __builtin_amdgcn_mfma_f32_16x16x32_bf16(afrag, bfrag, acc[t], 0, 0, 0);
            }
        }
#pragma unroll
        for (int t = 0; t < 4; ++t)
#pragma unroll
            for (int r = 0; r < 4; ++r) {
                int row = rowbase + quad * 4 + r;
                if (row < NNODES) pr.out[(size_t)row * OO + t * 16 + l15] = acc[t][r];
            }
    }
}

// ===========================================================================
// Fallback path: the proven R8 3-kernel pipeline (identical semantics).
// ===========================================================================
__global__ void k_pre(Params pr) {
    __shared__ short W[AA * 200];
    int tid = threadIdx.x;
    int wave = tid >> 6, lane = tid & 63;
    int quad = lane >> 4, l15 = lane & 15;

    if (blockIdx.x < XSB) {
        int rowbase_blk = blockIdx.x * 64;
        {
            const short8 z = short8{0,0,0,0,0,0,0,0};
            int base = rowbase_blk * DD + tid * 16;
            int row0 = rowbase_blk + (tid >> 2);
            if (row0 < NNODES) {
                *(short8*)(pr.agg + base) = z;
                *(short8*)(pr.agg + base + 8) = z;
            }
        }
        for (int idx = tid; idx < AA * DD; idx += 256) {
            int a = idx >> 6, d = idx & 63;
            W[a * 72 + d] = (short)f2bf(pr.Ws_W[idx]);
        }
        __syncthreads();
        int rowbase = rowbase_blk + wave * 16;
        int row_a = rowbase + l15;
        f32x4 acc[4];
        for (int t = 0; t < 4; ++t) { acc[t][0]=acc[t][1]=acc[t][2]=acc[t][3]=0.f; }
#pragma unroll
        for (int ks = 0; ks < 2; ++ks) {
            int ka = ks * 32 + quad * 8;
            short8 afrag;
            if (row_a < NNODES) {
                afrag = load8_cvt(pr.hidden + (size_t)row_a * DD + ka);
                *(short8*)(pr.hidden_bf + (size_t)row_a * DD + ka) = afrag;
            } else {
                afrag = short8{0,0,0,0,0,0,0,0};
            }
#pragma unroll
            for (int t = 0; t < 4; ++t) {
                short8 bfrag = *(const short8*)&W[(t * 16 + l15) * 72 + ka];
                acc[t] = __builtin_amdgcn_mfma_f32_16x16x32_bf16(afrag, bfrag, acc[t], 0, 0, 0);
            }
        }
#pragma unroll
        for (int t = 0; t < 4; ++t)
#pragma unroll
            for (int r = 0; r < 4; ++r) {
                int row = rowbase + quad * 4 + r;
                if (row < NNODES)
                    pr.Xs[(size_t)row * AA + t * 16 + l15] = (short)f2bf(acc[t][r]);
            }
    } else {
        int pb = blockIdx.x - XSB;
        for (int idx = tid; idx < AA * 192; idx += 256) {
            int a = idx / 192, k = idx - a * 192;
            float v = (k < 64) ? pr.Wq_W[a * 64 + k]
                    : (k < 128) ? pr.Wr_W[a * 64 + (k - 64)]
                                : pr.Wqr_W[a * 64 + (k - 128)];
            W[a * 200 + k] = (short)f2bf(v);
        }
        __syncthreads();
        int pairbase = pb * 64 + wave * 16;
        int mypair = pairbase + l15;
        int q = mypair / RN;
        int r = mypair - q * RN;
        const float* hq = pr.q_emb + (size_t)q * DD;
        const float* hr = pr.rela  + (size_t)r * DD;
        f32x4 acc[4];
#pragma unroll
        for (int t = 0; t < 4; ++t) {
            float b = pr.Ws_b[t * 16 + l15];
            acc[t][0] = acc[t][1] = acc[t][2] = acc[t][3] = b;
        }
#pragma unroll
        for (int ks = 0; ks < 6; ++ks) {
            int ka = ks * 32 + quad * 8;
            short8 afrag;
            if (ka < 64)       afrag = load8_cvt(hq + ka);
            else if (ka < 128) afrag = load8_cvt(hr + (ka - 64));
            else               afrag = load8_cvt_prod(hq + (ka - 128), hr + (ka - 128));
#pragma unroll
            for (int t = 0; t < 4; ++t) {
                short8 bfrag = *(const short8*)&W[(t * 16 + l15) * 200 + ka];
                acc[t] = __builtin_amdgcn_mfma_f32_16x16x32_bf16(afrag, bfrag, acc[t], 0, 0, 0);
            }
        }
#pragma unroll
        for (int t = 0; t < 4; ++t)
#pragma unroll
            for (int rg = 0; rg < 4; ++rg) {
                int row = pairbase + quad * 4 + rg;
                pr.P[(size_t)row * AA + t * 16 + l15] = (short)f2bf(acc[t][rg]);
            }
    }
}

__global__ void k_edge(Params pr) {
    int tid  = threadIdx.x;
    int wave = tid >> 6, lane = tid & 63;
    int l32  = lane & 31;
    int half = lane >> 5;
    size_t e = (size_t)blockIdx.x * 8 + wave * 2 + half;

    const int* ep = pr.edges + e * 6;
    int q = ep[0];
    int r = ep[2];
    int2 so = *(const int2*)&ep[4];
    int sub = so.x, obj = so.y;

    int c2 = 2 * l32;
    unsigned xs_u = *(const unsigned*)&pr.Xs[(size_t)sub * AA + c2];
    unsigned pp_u = *(const unsigned*)&pr.P[((size_t)q * RN + r) * AA + c2];
    f32x2 xs = bfpair2f(xs_u);
    f32x2 pp = bfpair2f(pp_u);
    f32x2 wa = *(const f32x2*)&pr.wa_W[c2];

    float v = fmaxf(xs[0] + pp[0], 0.f) * wa[0]
            + fmaxf(xs[1] + pp[1], 0.f) * wa[1];
#pragma unroll
    for (int off = 16; off > 0; off >>= 1) v += __shfl_xor(v, off, 64);
    float alpha = 1.f / (1.f + __expf(-(v + pr.wa_b[0])));
    if (l32 == 0) pr.alpha_out[e] = alpha;

    unsigned hs_u = *(const unsigned*)&pr.hidden_bf[(size_t)sub * DD + c2];
    f32x2 hs = bfpair2f(hs_u);
    f32x2 hr = *(const f32x2*)&pr.rela[(size_t)r * DD + c2];
    short2v m;
    m[0] = (short)f2bf(alpha * hs[0] * hr[0]);
    m[1] = (short)f2bf(alpha * hs[1] * hr[1]);
    atomic_pk_add_bf16(pr.agg + (size_t)obj * DD + c2, m);
}

__global__ void k_out(Params pr) {
    __shared__ short W[OO * 72];
    int tid = threadIdx.x;
    for (int idx = tid; idx < OO * DD; idx += 256) {
        int o = idx >> 6, d = idx & 63;
        W[o * 72 + d] = (short)f2bf(pr.Wh_W[idx]);
    }
    __syncthreads();
    int wave = tid >> 6, lane = tid & 63;
    int quad = lane >> 4, l15 = lane & 15;
    int rowbase = blockIdx.x * 64 + wave * 16;
    int row_a = rowbase + l15;
    f32x4 acc[4];
    for (int t = 0; t < 4; ++t) { acc[t][0]=acc[t][1]=acc[t][2]=acc[t][3]=0.f; }
#pragma unroll
    for (int ks = 0; ks < 2; ++ks) {
        int ka = ks * 32 + quad * 8;
        short8 afrag;
        if (row_a < NNODES) afrag = *(const short8*)(pr.agg + (size_t)row_a * DD + ka);
        else                afrag = short8{0,0,0,0,0,0,0,0};
#pragma unroll
        for (int t = 0; t < 4; ++t) {
            short8 bfrag = *(const short8*)&W[(t * 16 + l15) * 72 + ka];
            acc[t] = __builtin_amdgcn_mfma_f32_16x16x32_bf16(afrag, bfrag, acc[t], 0, 0, 0);
        }
    }
#pragma unroll
    for (int t = 0; t < 4; ++t)
#pragma unroll
        for (int r = 0; r < 4; ++r) {
            int row = rowbase + quad * 4 + r;
            if (row < NNODES) pr.out[(size_t)row * OO + t * 16 + l15] = acc[t][r];
        }
}

// ---------------------------------------------------------------------------
extern "C" void kernel_launch(void* const* d_in, const int* in_sizes, int n_in,
                              void* d_out, int out_size, void* d_ws, size_t ws_size,
                              hipStream_t stream) {
    Params pr;
    pr.q_emb  = (const float*)d_in[1];
    pr.rela   = (const float*)d_in[2];
    pr.hidden = (const float*)d_in[3];
    pr.edges  = (const int*)d_in[4];
    pr.Ws_W   = (const float*)d_in[6];
    pr.Ws_b   = (const float*)d_in[7];
    pr.Wr_W   = (const float*)d_in[8];
    pr.Wq_W   = (const float*)d_in[9];
    pr.Wqr_W  = (const float*)d_in[10];
    pr.wa_W   = (const float*)d_in[11];
    pr.wa_b   = (const float*)d_in[12];
    pr.Wh_W   = (const float*)d_in[13];

    short* Xs        = (short*)d_ws;                         // N*A   bf16
    short* P         = Xs + (size_t)NNODES * AA;             // Q*R*A bf16
    short* hidden_bf = P + (size_t)QN * RN * AA;             // N*D   bf16
    short* agg       = hidden_bf + (size_t)NNODES * DD;      // N*D   bf16
    pr.Xs = Xs; pr.P = P; pr.hidden_bf = hidden_bf; pr.agg = agg;

    pr.out       = (float*)d_out;                            // hidden_new (N*O)
    pr.alpha_out = pr.out + (size_t)NNODES * OO;             // alpha (E)

    // --- try cooperative mega-kernel; fall back to 3-kernel path on any error
    hipError_t err = hipErrorUnknown;
    int dev = 0;
    if (hipGetDevice(&dev) == hipSuccess) {
        int coop = 0, nCU = 0, perCU = 0;
        (void)hipDeviceGetAttribute(&coop, hipDeviceAttributeCooperativeLaunch, dev);
        (void)hipDeviceGetAttribute(&nCU, hipDeviceAttributeMultiprocessorCount, dev);
        (void)hipOccupancyMaxActiveBlocksPerMultiprocessor(&perCU, mega, 256, 0);
        if (coop && nCU > 0 && perCU > 0) {
            int grid = perCU * nCU;
            if (grid > 2048) grid = 2048;
            void* args[] = { &pr };
            err = hipLaunchCooperativeKernel((const void*)mega, dim3(grid), dim3(256),
                                             args, 0, stream);
        }
    }
    if (err != hipSuccess) {
        k_pre<<<XSB + PB, 256, 0, stream>>>(pr);
        k_edge<<<EVB, 256, 0, stream>>>(pr);
        k_out<<<XSB, 256, 0, stream>>>(pr);
    }
}

// Round 11
// 203.887 us; speedup vs baseline: 2.5015x; 2.5015x over previous
//
#include <hip/hip_runtime.h>
#include <hip/hip_bf16.h>

#define EDGES  500000
#define NNODES 100000
#define QN     256
#define RN     401
#define DD     64
#define AA     64
#define OO     64
#define XSB    1563      // ceil(NNODES/64) blocks for xs/out phases
#define PB     1604      // (QN*RN)/64 blocks for p-phase (exact)
#define EVB    62500     // EDGES/8 blocks for edge kernel (exact)

typedef __attribute__((ext_vector_type(8))) short short8;
typedef __attribute__((ext_vector_type(2))) short short2v;
typedef __attribute__((ext_vector_type(4))) float f32x4;
typedef __attribute__((ext_vector_type(2))) float f32x2;

__device__ inline unsigned short f2bf(float f) {
    union { float f; unsigned int u; } v; v.f = f;
    unsigned int u = v.u;
    u += 0x7FFFu + ((u >> 16) & 1u);   // round-to-nearest-even
    return (unsigned short)(u >> 16);
}

__device__ inline f32x2 bfpair2f(unsigned int u) {
    union { unsigned int i; float f; } lo, hi;
    lo.i = u << 16;
    hi.i = u & 0xFFFF0000u;
    f32x2 r; r[0] = lo.f; r[1] = hi.f; return r;
}

__device__ inline short8 load8_cvt(const float* __restrict__ p) {
    f32x4 x0 = ((const f32x4*)p)[0];
    f32x4 x1 = ((const f32x4*)p)[1];
    short8 r;
    r[0] = (short)f2bf(x0[0]); r[1] = (short)f2bf(x0[1]);
    r[2] = (short)f2bf(x0[2]); r[3] = (short)f2bf(x0[3]);
    r[4] = (short)f2bf(x1[0]); r[5] = (short)f2bf(x1[1]);
    r[6] = (short)f2bf(x1[2]); r[7] = (short)f2bf(x1[3]);
    return r;
}

__device__ inline short8 load8_cvt_prod(const float* __restrict__ pa,
                                        const float* __restrict__ pb) {
    f32x4 a0 = ((const f32x4*)pa)[0];
    f32x4 a1 = ((const f32x4*)pa)[1];
    f32x4 b0 = ((const f32x4*)pb)[0];
    f32x4 b1 = ((const f32x4*)pb)[1];
    short8 r;
    r[0] = (short)f2bf(a0[0]*b0[0]); r[1] = (short)f2bf(a0[1]*b0[1]);
    r[2] = (short)f2bf(a0[2]*b0[2]); r[3] = (short)f2bf(a0[3]*b0[3]);
    r[4] = (short)f2bf(a1[0]*b1[0]); r[5] = (short)f2bf(a1[1]*b1[1]);
    r[6] = (short)f2bf(a1[2]*b1[2]); r[7] = (short)f2bf(a1[3]*b1[3]);
    return r;
}

// packed bf16x2 atomic add (global_atomic_pk_add_bf16, gfx90a+/CDNA4)
__device__ inline void atomic_pk_add_bf16(short* addr, short2v v) {
#if __has_builtin(__builtin_amdgcn_global_atomic_fadd_v2bf16)
    __builtin_amdgcn_global_atomic_fadd_v2bf16(
        (__attribute__((address_space(1))) short2v*)addr, v);
#else
    asm volatile("global_atomic_pk_add_bf16 %0, %1, off"
                 :: "v"(addr), "v"(v) : "memory");
#endif
}

struct Params {
    const float* hidden; const float* Ws_W; const float* q_emb; const float* rela;
    const float* Wq_W;   const float* Wr_W; const float* Wqr_W; const float* Ws_b;
    const int*   edges;  const float* wa_W; const float* wa_b;  const float* Wh_W;
    short* Xs; short* hidden_bf; short* P; short* agg;
    float* out; float* alpha_out;
};

// ---------------------------------------------------------------------------
// K_PRE: blocks [0,XSB): Xs = hidden @ Ws^T + hidden_bf + zero agg.
//        blocks [XSB,XSB+PB): P = Ws_b + concat(hq,hr,hq*hr) @ W3^T (K=192).
// Epilogues: C-fragments -> LDS tile -> coalesced short8 stores (2/lane).
// ---------------------------------------------------------------------------
__global__ void k_pre(Params pr) {
    __shared__ short W[AA * 200];          // 25600 B (xs phase uses 72-stride part)
    __shared__ short stage[4][16 * 72];    // 9216 B, per-wave 16x64 bf16 tile (+pad)
    int tid = threadIdx.x;
    int wave = tid >> 6, lane = tid & 63;
    int quad = lane >> 4, l15 = lane & 15;
    short* st = stage[wave];

    if (blockIdx.x < XSB) {
        // ---------------- xs phase ----------------
        int rowbase_blk = blockIdx.x * 64;
        {   // zero agg rows owned by this block (wide stores)
            const short8 z = short8{0,0,0,0,0,0,0,0};
            int base = rowbase_blk * DD + tid * 16;
            int row0 = rowbase_blk + (tid >> 2);
            if (row0 < NNODES) {
                *(short8*)(pr.agg + base) = z;
                *(short8*)(pr.agg + base + 8) = z;
            }
        }
        for (int idx = tid; idx < AA * DD; idx += 256) {
            int a = idx >> 6, d = idx & 63;
            W[a * 72 + d] = (short)f2bf(pr.Ws_W[idx]);
        }
        __syncthreads();
        int rowbase = rowbase_blk + wave * 16;
        int row_a = rowbase + l15;
        f32x4 acc[4];
        for (int t = 0; t < 4; ++t) { acc[t][0]=acc[t][1]=acc[t][2]=acc[t][3]=0.f; }
#pragma unroll
        for (int ks = 0; ks < 2; ++ks) {
            int ka = ks * 32 + quad * 8;
            short8 afrag;
            if (row_a < NNODES) {
                afrag = load8_cvt(pr.hidden + (size_t)row_a * DD + ka);
                *(short8*)(pr.hidden_bf + (size_t)row_a * DD + ka) = afrag;
            } else {
                afrag = short8{0,0,0,0,0,0,0,0};
            }
#pragma unroll
            for (int t = 0; t < 4; ++t) {
                short8 bfrag = *(const short8*)&W[(t * 16 + l15) * 72 + ka];
                acc[t] = __builtin_amdgcn_mfma_f32_16x16x32_bf16(afrag, bfrag, acc[t], 0, 0, 0);
            }
        }
        // epilogue: stage -> wide stores (2 short8 stores/lane, coalesced)
#pragma unroll
        for (int t = 0; t < 4; ++t)
#pragma unroll
            for (int r = 0; r < 4; ++r)
                st[(quad * 4 + r) * 72 + t * 16 + l15] = (short)f2bf(acc[t][r]);
        asm volatile("s_waitcnt lgkmcnt(0)" ::: "memory");
#pragma unroll
        for (int i = 0; i < 2; ++i) {
            int rr = i * 8 + (lane >> 3);
            int cc = (lane & 7) * 8;
            int grow = rowbase + rr;
            if (grow < NNODES) {
                short8 v = *(short8*)&st[rr * 72 + cc];
                *(short8*)&pr.Xs[(size_t)grow * AA + cc] = v;
            }
        }
    } else {
        // ---------------- p phase ----------------
        int pb = blockIdx.x - XSB;
        for (int idx = tid; idx < AA * 192; idx += 256) {
            int a = idx / 192, k = idx - a * 192;
            float v = (k < 64) ? pr.Wq_W[a * 64 + k]
                    : (k < 128) ? pr.Wr_W[a * 64 + (k - 64)]
                                : pr.Wqr_W[a * 64 + (k - 128)];
            W[a * 200 + k] = (short)f2bf(v);
        }
        __syncthreads();
        int pairbase = pb * 64 + wave * 16;
        int mypair = pairbase + l15;
        int q = mypair / RN;
        int r = mypair - q * RN;
        const float* hq = pr.q_emb + (size_t)q * DD;
        const float* hr = pr.rela  + (size_t)r * DD;
        f32x4 acc[4];
#pragma unroll
        for (int t = 0; t < 4; ++t) {
            float b = pr.Ws_b[t * 16 + l15];
            acc[t][0] = acc[t][1] = acc[t][2] = acc[t][3] = b;
        }
#pragma unroll
        for (int ks = 0; ks < 6; ++ks) {
            int ka = ks * 32 + quad * 8;
            short8 afrag;
            if (ka < 64)       afrag = load8_cvt(hq + ka);
            else if (ka < 128) afrag = load8_cvt(hr + (ka - 64));
            else               afrag = load8_cvt_prod(hq + (ka - 128), hr + (ka - 128));
#pragma unroll
            for (int t = 0; t < 4; ++t) {
                short8 bfrag = *(const short8*)&W[(t * 16 + l15) * 200 + ka];
                acc[t] = __builtin_amdgcn_mfma_f32_16x16x32_bf16(afrag, bfrag, acc[t], 0, 0, 0);
            }
        }
        // epilogue: stage -> wide stores (no bounds check; PB grid is exact)
#pragma unroll
        for (int t = 0; t < 4; ++t)
#pragma unroll
            for (int rg = 0; rg < 4; ++rg)
                st[(quad * 4 + rg) * 72 + t * 16 + l15] = (short)f2bf(acc[t][rg]);
        asm volatile("s_waitcnt lgkmcnt(0)" ::: "memory");
#pragma unroll
        for (int i = 0; i < 2; ++i) {
            int rr = i * 8 + (lane >> 3);
            int cc = (lane & 7) * 8;
            int prow = pairbase + rr;
            short8 v = *(short8*)&st[rr * 72 + cc];
            *(short8*)&pr.P[(size_t)prow * AA + cc] = v;
        }
    }
}

// ---------------------------------------------------------------------------
// K_EDGE: 2 edges per wave (32 lanes / edge, bf16x2 per lane), bf16 pk atomics.
// ---------------------------------------------------------------------------
__global__ void k_edge(Params pr) {
    int tid  = threadIdx.x;
    int wave = tid >> 6, lane = tid & 63;
    int l32  = lane & 31;
    int half = lane >> 5;
    size_t e = (size_t)blockIdx.x * 8 + wave * 2 + half;

    const int* ep = pr.edges + e * 6;
    int q = ep[0];
    int r = ep[2];
    int2 so = *(const int2*)&ep[4];          // {sub, obj}
    int sub = so.x, obj = so.y;

    int c2 = 2 * l32;
    unsigned xs_u = *(const unsigned*)&pr.Xs[(size_t)sub * AA + c2];
    unsigned pp_u = *(const unsigned*)&pr.P[((size_t)q * RN + r) * AA + c2];
    f32x2 xs = bfpair2f(xs_u);
    f32x2 pp = bfpair2f(pp_u);
    f32x2 wa = *(const f32x2*)&pr.wa_W[c2];

    float v = fmaxf(xs[0] + pp[0], 0.f) * wa[0]
            + fmaxf(xs[1] + pp[1], 0.f) * wa[1];
#pragma unroll
    for (int off = 16; off > 0; off >>= 1) v += __shfl_xor(v, off, 64); // stays in half
    float alpha = 1.f / (1.f + __expf(-(v + pr.wa_b[0])));
    if (l32 == 0) pr.alpha_out[e] = alpha;

    unsigned hs_u = *(const unsigned*)&pr.hidden_bf[(size_t)sub * DD + c2];
    f32x2 hs = bfpair2f(hs_u);
    f32x2 hr = *(const f32x2*)&pr.rela[(size_t)r * DD + c2];
    short2v m;
    m[0] = (short)f2bf(alpha * hs[0] * hr[0]);
    m[1] = (short)f2bf(alpha * hs[1] * hr[1]);
    atomic_pk_add_bf16(pr.agg + (size_t)obj * DD + c2, m);
}

// ---------------------------------------------------------------------------
// K_OUT: out = agg @ Wh^T (MFMA, K=64; agg bf16). LDS-staged f32x4 stores.
// ---------------------------------------------------------------------------
__global__ void k_out(Params pr) {
    __shared__ short W[OO * 72];           // 9216 B
    __shared__ float stF[4][16 * 68];      // 17408 B, per-wave 16x64 f32 tile (+pad)
    int tid = threadIdx.x;
    for (int idx = tid; idx < OO * DD; idx += 256) {
        int o = idx >> 6, d = idx & 63;
        W[o * 72 + d] = (short)f2bf(pr.Wh_W[idx]);
    }
    __syncthreads();
    int wave = tid >> 6, lane = tid & 63;
    int quad = lane >> 4, l15 = lane & 15;
    int rowbase = blockIdx.x * 64 + wave * 16;
    int row_a = rowbase + l15;
    float* st = stF[wave];

    f32x4 acc[4];
    for (int t = 0; t < 4; ++t) { acc[t][0]=acc[t][1]=acc[t][2]=acc[t][3]=0.f; }
#pragma unroll
    for (int ks = 0; ks < 2; ++ks) {
        int ka = ks * 32 + quad * 8;
        short8 afrag;
        if (row_a < NNODES) afrag = *(const short8*)(pr.agg + (size_t)row_a * DD + ka);
        else                afrag = short8{0,0,0,0,0,0,0,0};
#pragma unroll
        for (int t = 0; t < 4; ++t) {
            short8 bfrag = *(const short8*)&W[(t * 16 + l15) * 72 + ka];
            acc[t] = __builtin_amdgcn_mfma_f32_16x16x32_bf16(afrag, bfrag, acc[t], 0, 0, 0);
        }
    }
    // epilogue: stage -> 4 coalesced f32x4 stores/lane
#pragma unroll
    for (int t = 0; t < 4; ++t)
#pragma unroll
        for (int r = 0; r < 4; ++r)
            st[(quad * 4 + r) * 68 + t * 16 + l15] = acc[t][r];
    asm volatile("s_waitcnt lgkmcnt(0)" ::: "memory");
#pragma unroll
    for (int i = 0; i < 4; ++i) {
        int rr = i * 4 + (lane >> 4);
        int cc = (lane & 15) * 4;
        int grow = rowbase + rr;
        if (grow < NNODES) {
            f32x4 v = *(f32x4*)&st[rr * 68 + cc];
            *(f32x4*)&pr.out[(size_t)grow * OO + cc] = v;
        }
    }
}

// ---------------------------------------------------------------------------
extern "C" void kernel_launch(void* const* d_in, const int* in_sizes, int n_in,
                              void* d_out, int out_size, void* d_ws, size_t ws_size,
                              hipStream_t stream) {
    Params pr;
    pr.q_emb  = (const float*)d_in[1];
    pr.rela   = (const float*)d_in[2];
    pr.hidden = (const float*)d_in[3];
    pr.edges  = (const int*)d_in[4];
    pr.Ws_W   = (const float*)d_in[6];
    pr.Ws_b   = (const float*)d_in[7];
    pr.Wr_W   = (const float*)d_in[8];
    pr.Wq_W   = (const float*)d_in[9];
    pr.Wqr_W  = (const float*)d_in[10];
    pr.wa_W   = (const float*)d_in[11];
    pr.wa_b   = (const float*)d_in[12];
    pr.Wh_W   = (const float*)d_in[13];

    short* Xs        = (short*)d_ws;                         // N*A   bf16
    short* P         = Xs + (size_t)NNODES * AA;             // Q*R*A bf16
    short* hidden_bf = P + (size_t)QN * RN * AA;             // N*D   bf16
    short* agg       = hidden_bf + (size_t)NNODES * DD;      // N*D   bf16
    pr.Xs = Xs; pr.P = P; pr.hidden_bf = hidden_bf; pr.agg = agg;

    pr.out       = (float*)d_out;                            // hidden_new (N*O)
    pr.alpha_out = pr.out + (size_t)NNODES * OO;             // alpha (E)

    k_pre<<<XSB + PB, 256, 0, stream>>>(pr);
    k_edge<<<EVB, 256, 0, stream>>>(pr);
    k_out<<<XSB, 256, 0, stream>>>(pr);
}